// Round 1
// baseline (1132.474 us; speedup 1.0000x reference)
//
#include <hip/hip_runtime.h>
#include <math.h>

#define HIDDEN 64
#define LATENT 32
#define HEADS 4
#define IN_DIM 128
#define NUM_CLASSES 10
#define NUM_GRAPHS 64
#define NEG_SLOPE 0.2f
#define HC 256  // HEADS*HIDDEN

// ---------------- utility ----------------
__global__ void k_fill(float* __restrict__ p, int n, float v) {
    int i = blockIdx.x * blockDim.x + threadIdx.x;
    if (i < n) p[i] = v;
}

// sum edge_attr columns (3) -> ea_sum[3]
__global__ void k_easum(const float* __restrict__ ea, int E, float* __restrict__ ea_sum) {
    float s0 = 0.f, s1 = 0.f, s2 = 0.f;
    for (int e = blockIdx.x * blockDim.x + threadIdx.x; e < E; e += gridDim.x * blockDim.x) {
        s0 += ea[e * 3 + 0];
        s1 += ea[e * 3 + 1];
        s2 += ea[e * 3 + 2];
    }
    for (int off = 32; off; off >>= 1) {
        s0 += __shfl_xor(s0, off);
        s1 += __shfl_xor(s1, off);
        s2 += __shfl_xor(s2, off);
    }
    if ((threadIdx.x & 63) == 0) {
        atomicAdd(&ea_sum[0], s0);
        atomicAdd(&ea_sum[1], s1);
        atomicAdd(&ea_sum[2], s2);
    }
}

// ---------------- dual GEMM: xl = X@Wl, xr = X@Wr;  X:[N,K], W:[K,256] ----------------
template <int K, int NPB>
__global__ void k_dual_gemm(const float* __restrict__ X, const float* __restrict__ Wl,
                            const float* __restrict__ Wr, float* __restrict__ xl,
                            float* __restrict__ xr, int N) {
    __shared__ float sx[NPB][K];
    int node0 = blockIdx.x * NPB;
    int tid = threadIdx.x;
    for (int i = tid; i < NPB * K; i += blockDim.x) {
        int n = i / K, k = i % K;
        int gn = node0 + n;
        sx[n][k] = (gn < N) ? X[(long)gn * K + k] : 0.f;
    }
    __syncthreads();
    int col = tid;  // 0..255
    float accl[NPB], accr[NPB];
#pragma unroll
    for (int n = 0; n < NPB; n++) { accl[n] = 0.f; accr[n] = 0.f; }
    for (int k = 0; k < K; k++) {
        float wl = Wl[k * HC + col];
        float wr = Wr[k * HC + col];
#pragma unroll
        for (int n = 0; n < NPB; n++) {
            accl[n] += sx[n][k] * wl;
            accr[n] += sx[n][k] * wr;
        }
    }
#pragma unroll
    for (int n = 0; n < NPB; n++) {
        int gn = node0 + n;
        if (gn < N) {
            xl[(long)gn * HC + col] = accl[n];
            xr[(long)gn * HC + col] = accr[n];
        }
    }
}

// ---------------- edge logits (one wave per edge) + atomic segment-max ----------------
__global__ void k_edge_logits(const float* __restrict__ xl, const float* __restrict__ xr,
                              const int* __restrict__ ei, const float* __restrict__ ea,
                              const float* __restrict__ ea_sum, const float* __restrict__ We,
                              const float* __restrict__ att, float* __restrict__ elog,
                              int* __restrict__ nmax, int E0, int ET) {
    int wid = (blockIdx.x * blockDim.x + threadIdx.x) >> 6;
    int lane = threadIdx.x & 63;
    if (wid >= ET) return;
    int src, dst;
    float a0, a1, a2;
    if (wid < E0) {
        src = ei[wid];
        dst = ei[E0 + wid];
        a0 = ea[wid * 3 + 0];
        a1 = ea[wid * 3 + 1];
        a2 = ea[wid * 3 + 2];
    } else {
        src = wid - E0;
        dst = src;
        float inv = 1.f / (float)E0;
        a0 = ea_sum[0] * inv;
        a1 = ea_sum[1] * inv;
        a2 = ea_sum[2] * inv;
    }
    const float* xls = xl + (long)src * HC;
    const float* xrd = xr + (long)dst * HC;
    float p[HEADS];
#pragma unroll
    for (int h = 0; h < HEADS; h++) {
        int idx = h * 64 + lane;
        float e = a0 * We[idx] + a1 * We[HC + idx] + a2 * We[2 * HC + idx];
        float s = xls[idx] + xrd[idx] + e;
        s = (s > 0.f) ? s : NEG_SLOPE * s;
        p[h] = s * att[idx];
    }
    for (int off = 32; off; off >>= 1) {
#pragma unroll
        for (int h = 0; h < HEADS; h++) p[h] += __shfl_xor(p[h], off);
    }
    if (lane == 0) {
#pragma unroll
        for (int h = 0; h < HEADS; h++) {
            float v = p[h];
            elog[(long)wid * HEADS + h] = v;
            int* addr = &nmax[dst * HEADS + h];
            if (v >= 0.f)
                atomicMax(addr, __float_as_int(v));
            else
                atomicMin((unsigned int*)addr, __float_as_uint(v));
        }
    }
}

// ---------------- exp(logit - max) + atomic denom ----------------
__global__ void k_edge_exp(float* __restrict__ elog, const int* __restrict__ ei,
                           const int* __restrict__ nmax, float* __restrict__ ndenom, int E0,
                           int ET) {
    int i = blockIdx.x * blockDim.x + threadIdx.x;
    if (i >= ET * HEADS) return;
    int e = i >> 2, h = i & 3;
    int dst = (e < E0) ? ei[E0 + e] : (e - E0);
    float m = __int_as_float(nmax[dst * HEADS + h]);
    float ex = expf(elog[i] - m);
    elog[i] = ex;
    atomicAdd(&ndenom[dst * HEADS + h], ex);
}

// ---------------- aggregate: hacc[dst][c] += (1/4) * sum_h alpha[e,h]*xl[src][h,c] ----------------
__global__ void k_aggregate(const float* __restrict__ xl, const float* __restrict__ elog,
                            const float* __restrict__ ndenom, const int* __restrict__ ei,
                            float* __restrict__ hacc, int E0, int ET) {
    int wid = (blockIdx.x * blockDim.x + threadIdx.x) >> 6;
    int lane = threadIdx.x & 63;
    if (wid >= ET) return;
    int src, dst;
    if (wid < E0) {
        src = ei[wid];
        dst = ei[E0 + wid];
    } else {
        src = wid - E0;
        dst = src;
    }
    float alpha[HEADS];
#pragma unroll
    for (int h = 0; h < HEADS; h++)
        alpha[h] = elog[(long)wid * HEADS + h] / ndenom[dst * HEADS + h];
    const float* xls = xl + (long)src * HC;
    float acc = 0.f;
#pragma unroll
    for (int h = 0; h < HEADS; h++) acc += alpha[h] * xls[h * 64 + lane];
    atomicAdd(&hacc[(long)dst * 64 + lane], 0.25f * acc);
}

// ---------------- bias + relu ----------------
__global__ void k_bias_relu(const float* __restrict__ hacc, const float* __restrict__ b,
                            float* __restrict__ hout, int n64) {
    int i = blockIdx.x * blockDim.x + threadIdx.x;
    if (i >= n64) return;
    float v = hacc[i] + b[i & 63];
    hout[i] = v > 0.f ? v : 0.f;
}

// ---------------- z = h @ W_mu + b_mu  (64 -> 32) ----------------
__global__ void k_mu(const float* __restrict__ h, const float* __restrict__ Wmu,
                     const float* __restrict__ bmu, float* __restrict__ z, int N) {
    int i = blockIdx.x * blockDim.x + threadIdx.x;
    if (i >= N * LATENT) return;
    int n = i >> 5, j = i & 31;
    const float* hr = h + (long)n * 64;
    float acc = bmu[j];
#pragma unroll
    for (int k = 0; k < 64; k++) acc += hr[k] * Wmu[k * LATENT + j];
    z[i] = acc;
}

// ---------------- recon = z @ W_dec + b_dec  (32 -> 128) ----------------
__global__ void k_dec(const float* __restrict__ z, const float* __restrict__ W,
                      const float* __restrict__ b, float* __restrict__ out, int N) {
    int i = blockIdx.x * blockDim.x + threadIdx.x;
    if (i >= N * IN_DIM) return;
    int n = i >> 7, j = i & 127;
    const float* zr = z + (long)n * LATENT;
    float acc = b[j];
#pragma unroll
    for (int k = 0; k < LATENT; k++) acc += zr[k] * W[k * IN_DIM + j];
    out[i] = acc;
}

// ---------------- link: half-wave (32 lanes) per original edge ----------------
__global__ void k_link(const float* __restrict__ z, const int* __restrict__ ei,
                       const float* __restrict__ w, float* __restrict__ link, int E0) {
    int t = blockIdx.x * blockDim.x + threadIdx.x;
    int e = t >> 5;
    int c = t & 31;
    if (e >= E0) return;
    int s = ei[e], d = ei[E0 + e];
    float v = z[(long)s * LATENT + c] * z[(long)d * LATENT + c] * w[c];
    for (int off = 16; off; off >>= 1) v += __shfl_xor(v, off);
    if (c == 0) link[e] = v;
}

// ---------------- global add pool ----------------
__global__ void k_pool(const float* __restrict__ z, const int* __restrict__ batch,
                       float* __restrict__ gemb, int N) {
    int i = blockIdx.x * blockDim.x + threadIdx.x;
    if (i >= N * LATENT) return;
    int n = i >> 5, j = i & 31;
    atomicAdd(&gemb[batch[n] * LATENT + j], z[i]);
}

// ---------------- classifier: logits = gemb @ W_cls + b_cls ----------------
__global__ void k_cls(const float* __restrict__ g, const float* __restrict__ W,
                      const float* __restrict__ b, float* __restrict__ out) {
    int i = blockIdx.x * blockDim.x + threadIdx.x;
    if (i >= NUM_GRAPHS * NUM_CLASSES) return;
    int gi = i / NUM_CLASSES, j = i % NUM_CLASSES;
    float acc = b[j];
#pragma unroll
    for (int k = 0; k < LATENT; k++) acc += g[gi * LATENT + k] * W[k * NUM_CLASSES + j];
    out[i] = acc;
}

extern "C" void kernel_launch(void* const* d_in, const int* in_sizes, int n_in, void* d_out,
                              int out_size, void* d_ws, size_t ws_size, hipStream_t stream) {
    const float* x = (const float*)d_in[0];
    const int* ei = (const int*)d_in[1];
    const float* ea = (const float*)d_in[2];
    const int* batch = (const int*)d_in[3];
    const float* Wl0 = (const float*)d_in[4];
    const float* Wr0 = (const float*)d_in[5];
    const float* We0 = (const float*)d_in[6];
    const float* att0 = (const float*)d_in[7];
    const float* b0 = (const float*)d_in[8];
    const float* Wl1 = (const float*)d_in[9];
    const float* Wr1 = (const float*)d_in[10];
    const float* We1 = (const float*)d_in[11];
    const float* att1 = (const float*)d_in[12];
    const float* b1 = (const float*)d_in[13];
    const float* Wmu = (const float*)d_in[14];
    const float* bmu = (const float*)d_in[15];
    const float* Wdec = (const float*)d_in[16];
    const float* bdec = (const float*)d_in[17];
    const float* Wcls = (const float*)d_in[18];
    const float* bcls = (const float*)d_in[19];
    const float* weight = (const float*)d_in[20];

    const int N = in_sizes[0] / IN_DIM;   // 50000
    const int E0 = in_sizes[1] / 2;       // 400000
    const int ET = E0 + N;                // with self-loops

    // workspace layout (floats)
    float* ws = (float*)d_ws;
    size_t o = 0;
    float* A = ws + o; o += (size_t)N * HC;        // xl  [N,256]
    float* B = ws + o; o += (size_t)N * HC;        // xr  [N,256]
    float* C = ws + o; o += (size_t)ET * HEADS;    // edge logits / exp [ET,4]
    float* nmaxf = ws + o; o += (size_t)N * HEADS; // segment max [N,4] (float bits)
    float* ndenom = ws + o; o += (size_t)N * HEADS;
    float* F = ws + o; o += (size_t)N * HIDDEN;    // aggregation accumulator
    float* G = ws + o; o += (size_t)N * HIDDEN;    // layer output h
    float* easum = ws + o; o += 16;
    float* gemb = ws + o; o += NUM_GRAPHS * LATENT;
    int* nmax = (int*)nmaxf;

    // output layout: z | recon | link | logits
    float* out = (float*)d_out;
    float* z_out = out;
    float* recon_out = out + (size_t)N * LATENT;
    float* link_out = recon_out + (size_t)N * IN_DIM;
    float* logits_out = link_out + (size_t)E0;

    const int TB = 256;
    const int edgeBlocks = (ET * 64 + TB - 1) / TB;  // one wave per edge

    // ---- init ----
    hipMemsetAsync(F, 0, (size_t)N * HIDDEN * sizeof(float), stream);
    hipMemsetAsync(ndenom, 0, (size_t)N * HEADS * sizeof(float), stream);
    hipMemsetAsync(easum, 0, 16 * sizeof(float), stream);
    hipMemsetAsync(gemb, 0, NUM_GRAPHS * LATENT * sizeof(float), stream);
    k_fill<<<(N * HEADS + TB - 1) / TB, TB, 0, stream>>>(nmaxf, N * HEADS, -INFINITY);
    k_easum<<<256, TB, 0, stream>>>(ea, E0, easum);

    // ---- layer 0 ----
    k_dual_gemm<IN_DIM, 8><<<(N + 7) / 8, TB, 0, stream>>>(x, Wl0, Wr0, A, B, N);
    k_edge_logits<<<edgeBlocks, TB, 0, stream>>>(A, B, ei, ea, easum, We0, att0, C, nmax, E0, ET);
    k_edge_exp<<<(ET * HEADS + TB - 1) / TB, TB, 0, stream>>>(C, ei, nmax, ndenom, E0, ET);
    k_aggregate<<<edgeBlocks, TB, 0, stream>>>(A, C, ndenom, ei, F, E0, ET);
    k_bias_relu<<<(N * HIDDEN + TB - 1) / TB, TB, 0, stream>>>(F, b0, G, N * HIDDEN);

    // re-init segment state for layer 1
    hipMemsetAsync(F, 0, (size_t)N * HIDDEN * sizeof(float), stream);
    hipMemsetAsync(ndenom, 0, (size_t)N * HEADS * sizeof(float), stream);
    k_fill<<<(N * HEADS + TB - 1) / TB, TB, 0, stream>>>(nmaxf, N * HEADS, -INFINITY);

    // ---- layer 1 ----
    k_dual_gemm<HIDDEN, 8><<<(N + 7) / 8, TB, 0, stream>>>(G, Wl1, Wr1, A, B, N);
    k_edge_logits<<<edgeBlocks, TB, 0, stream>>>(A, B, ei, ea, easum, We1, att1, C, nmax, E0, ET);
    k_edge_exp<<<(ET * HEADS + TB - 1) / TB, TB, 0, stream>>>(C, ei, nmax, ndenom, E0, ET);
    k_aggregate<<<edgeBlocks, TB, 0, stream>>>(A, C, ndenom, ei, F, E0, ET);
    k_bias_relu<<<(N * HIDDEN + TB - 1) / TB, TB, 0, stream>>>(F, b1, G, N * HIDDEN);

    // ---- heads ----
    k_mu<<<(N * LATENT + TB - 1) / TB, TB, 0, stream>>>(G, Wmu, bmu, z_out, N);
    k_dec<<<(N * IN_DIM + TB - 1) / TB, TB, 0, stream>>>(z_out, Wdec, bdec, recon_out, N);
    k_link<<<(E0 * 32 + TB - 1) / TB, TB, 0, stream>>>(z_out, ei, weight, link_out, E0);
    k_pool<<<(N * LATENT + TB - 1) / TB, TB, 0, stream>>>(z_out, batch, gemb, N);
    k_cls<<<(NUM_GRAPHS * NUM_CLASSES + TB - 1) / TB, TB, 0, stream>>>(gemb, Wcls, bcls, logits_out);
}

// Round 2
// 763.236 us; speedup vs baseline: 1.4838x; 1.4838x over previous
//
#include <hip/hip_runtime.h>
#include <math.h>

#define HIDDEN 64
#define LATENT 32
#define HEADS 4
#define IN_DIM 128
#define NUM_CLASSES 10
#define NUM_GRAPHS 64
#define NEG_SLOPE 0.2f
#define HC 256  // HEADS*HIDDEN

// ---------------- utility ----------------
// sum edge_attr columns (3) -> ea_sum[3]
__global__ void k_easum(const float* __restrict__ ea, int E, float* __restrict__ ea_sum) {
    float s0 = 0.f, s1 = 0.f, s2 = 0.f;
    for (int e = blockIdx.x * blockDim.x + threadIdx.x; e < E; e += gridDim.x * blockDim.x) {
        s0 += ea[e * 3 + 0];
        s1 += ea[e * 3 + 1];
        s2 += ea[e * 3 + 2];
    }
    for (int off = 32; off; off >>= 1) {
        s0 += __shfl_xor(s0, off);
        s1 += __shfl_xor(s1, off);
        s2 += __shfl_xor(s2, off);
    }
    if ((threadIdx.x & 63) == 0) {
        atomicAdd(&ea_sum[0], s0);
        atomicAdd(&ea_sum[1], s1);
        atomicAdd(&ea_sum[2], s2);
    }
}

// ---------------- CSR build ----------------
__global__ void k_hist(const int* __restrict__ ei, int* __restrict__ deg, int E0) {
    int e = blockIdx.x * blockDim.x + threadIdx.x;
    if (e < E0) atomicAdd(&deg[ei[E0 + e]], 1);
}

__global__ void k_scan1(const int* __restrict__ deg, int* __restrict__ off,
                        int* __restrict__ bsum, int N) {
    __shared__ int sh[256];
    int t = threadIdx.x, i = blockIdx.x * 256 + t;
    int v = (i < N) ? deg[i] : 0;
    sh[t] = v;
    __syncthreads();
    for (int d = 1; d < 256; d <<= 1) {
        int x = (t >= d) ? sh[t - d] : 0;
        __syncthreads();
        sh[t] += x;
        __syncthreads();
    }
    if (i < N) off[i] = sh[t] - v;  // exclusive
    if (t == 255) bsum[blockIdx.x] = sh[255];
}

__global__ void k_scan2(int* __restrict__ bsum, int nb) {
    __shared__ int sh[256];
    int t = threadIdx.x;
    int v = (t < nb) ? bsum[t] : 0;
    sh[t] = v;
    __syncthreads();
    for (int d = 1; d < 256; d <<= 1) {
        int x = (t >= d) ? sh[t - d] : 0;
        __syncthreads();
        sh[t] += x;
        __syncthreads();
    }
    if (t < nb) bsum[t] = sh[t] - v;  // exclusive block offsets
}

__global__ void k_scan3(int* __restrict__ off, const int* __restrict__ bsum,
                        int* __restrict__ cur, int N) {
    int i = blockIdx.x * 256 + threadIdx.x;
    if (i >= N) return;
    int o = off[i] + bsum[blockIdx.x];
    off[i] = o;
    cur[i] = o;
}

__global__ void k_scatter(const int* __restrict__ ei, const float* __restrict__ ea,
                          int* __restrict__ cur, int* __restrict__ csr_src,
                          float4* __restrict__ csr_a, int E0) {
    int e = blockIdx.x * blockDim.x + threadIdx.x;
    if (e >= E0) return;
    int dst = ei[E0 + e];
    int pos = atomicAdd(&cur[dst], 1);
    csr_src[pos] = ei[e];
    csr_a[pos] = make_float4(ea[e * 3], ea[e * 3 + 1], ea[e * 3 + 2], 0.f);
}

// ---------------- dual GEMM: xl = X@Wl, xr = X@Wr;  X:[N,K], W:[K,256] ----------------
template <int K, int NPB>
__global__ void k_dual_gemm(const float* __restrict__ X, const float* __restrict__ Wl,
                            const float* __restrict__ Wr, float* __restrict__ xl,
                            float* __restrict__ xr, int N) {
    __shared__ float sx[NPB][K];
    int node0 = blockIdx.x * NPB;
    int tid = threadIdx.x;
    for (int i = tid; i < NPB * K; i += blockDim.x) {
        int n = i / K, k = i % K;
        int gn = node0 + n;
        sx[n][k] = (gn < N) ? X[(long)gn * K + k] : 0.f;
    }
    __syncthreads();
    int col = tid;  // 0..255
    float accl[NPB], accr[NPB];
#pragma unroll
    for (int n = 0; n < NPB; n++) { accl[n] = 0.f; accr[n] = 0.f; }
    for (int k = 0; k < K; k++) {
        float wl = Wl[k * HC + col];
        float wr = Wr[k * HC + col];
#pragma unroll
        for (int n = 0; n < NPB; n++) {
            accl[n] += sx[n][k] * wl;
            accr[n] += sx[n][k] * wr;
        }
    }
#pragma unroll
    for (int n = 0; n < NPB; n++) {
        int gn = node0 + n;
        if (gn < N) {
            xl[(long)gn * HC + col] = accl[n];
            xr[(long)gn * HC + col] = accr[n];
        }
    }
}

// ---------------- fused GATv2 layer: wave per node, online softmax ----------------
// lane L holds cols idx = 4L..4L+3 of the 256-wide row; head h = L>>4, c = (L&15)*4+j
__global__ void k_gat(const float* __restrict__ xl, const float* __restrict__ xr,
                      const int* __restrict__ csr_src, const float4* __restrict__ csr_a,
                      const int* __restrict__ off, const int* __restrict__ deg,
                      const float* __restrict__ easum, float invE,
                      const float* __restrict__ We, const float* __restrict__ att,
                      const float* __restrict__ bias, float* __restrict__ out, int N) {
    int wid = (blockIdx.x * blockDim.x + threadIdx.x) >> 6;
    int L = threadIdx.x & 63;
    if (wid >= N) return;
    int n = wid;

    float4 xr4 = ((const float4*)(xr + (size_t)n * HC))[L];
    float4 w0 = ((const float4*)We)[L];
    float4 w1 = ((const float4*)(We + HC))[L];
    float4 w2 = ((const float4*)(We + 2 * HC))[L];
    float4 at = ((const float4*)att)[L];
    float am0 = easum[0] * invE, am1 = easum[1] * invE, am2 = easum[2] * invE;

    float m = -INFINITY, d = 0.f;
    float acc0 = 0.f, acc1 = 0.f, acc2 = 0.f, acc3 = 0.f;
    int base = off[n], cnt = deg[n];

    for (int i = -1; i < cnt; i++) {
        int src;
        float a0, a1, a2;
        if (i < 0) {  // self loop, mean edge attr
            src = n;
            a0 = am0; a1 = am1; a2 = am2;
        } else {
            src = csr_src[base + i];
            float4 a = csr_a[base + i];
            a0 = a.x; a1 = a.y; a2 = a.z;
        }
        float4 xs = ((const float4*)(xl + (size_t)src * HC))[L];
        float s0 = xs.x + xr4.x + (a0 * w0.x + a1 * w1.x + a2 * w2.x);
        float s1 = xs.y + xr4.y + (a0 * w0.y + a1 * w1.y + a2 * w2.y);
        float s2 = xs.z + xr4.z + (a0 * w0.z + a1 * w1.z + a2 * w2.z);
        float s3 = xs.w + xr4.w + (a0 * w0.w + a1 * w1.w + a2 * w2.w);
        s0 = (s0 > 0.f) ? s0 : NEG_SLOPE * s0;
        s1 = (s1 > 0.f) ? s1 : NEG_SLOPE * s1;
        s2 = (s2 > 0.f) ? s2 : NEG_SLOPE * s2;
        s3 = (s3 > 0.f) ? s3 : NEG_SLOPE * s3;
        float p = s0 * at.x + s1 * at.y + s2 * at.z + s3 * at.w;
        // segmented butterfly over the 16 lanes of this head
        p += __shfl_xor(p, 1);
        p += __shfl_xor(p, 2);
        p += __shfl_xor(p, 4);
        p += __shfl_xor(p, 8);
        // online softmax update (per lane; p is uniform within the 16-lane head group)
        float mn = fmaxf(m, p);
        float sc = __expf(m - mn);
        float ex = __expf(p - mn);
        d = d * sc + ex;
        acc0 = acc0 * sc + ex * xs.x;
        acc1 = acc1 * sc + ex * xs.y;
        acc2 = acc2 * sc + ex * xs.z;
        acc3 = acc3 * sc + ex * xs.w;
        m = mn;
    }
    float inv_d = 1.f / d;
    float v0 = acc0 * inv_d, v1 = acc1 * inv_d, v2 = acc2 * inv_d, v3 = acc3 * inv_d;
    // head-mean: sum over lanes L^16, L^32 (same c, different h)
    v0 += __shfl_xor(v0, 16); v1 += __shfl_xor(v1, 16);
    v2 += __shfl_xor(v2, 16); v3 += __shfl_xor(v3, 16);
    v0 += __shfl_xor(v0, 32); v1 += __shfl_xor(v1, 32);
    v2 += __shfl_xor(v2, 32); v3 += __shfl_xor(v3, 32);
    if (L < 16) {
        float4 bx = ((const float4*)bias)[L];
        float4 o;
        o.x = fmaxf(0.25f * v0 + bx.x, 0.f);
        o.y = fmaxf(0.25f * v1 + bx.y, 0.f);
        o.z = fmaxf(0.25f * v2 + bx.z, 0.f);
        o.w = fmaxf(0.25f * v3 + bx.w, 0.f);
        ((float4*)(out + (size_t)n * HIDDEN))[L] = o;
    }
}

// ---------------- z = h @ W_mu + b_mu  (64 -> 32) ----------------
__global__ void k_mu(const float* __restrict__ h, const float* __restrict__ Wmu,
                     const float* __restrict__ bmu, float* __restrict__ z, int N) {
    int i = blockIdx.x * blockDim.x + threadIdx.x;
    if (i >= N * LATENT) return;
    int n = i >> 5, j = i & 31;
    const float* hr = h + (long)n * 64;
    float acc = bmu[j];
#pragma unroll
    for (int k = 0; k < 64; k++) acc += hr[k] * Wmu[k * LATENT + j];
    z[i] = acc;
}

// ---------------- recon = z @ W_dec + b_dec  (32 -> 128) ----------------
__global__ void k_dec(const float* __restrict__ z, const float* __restrict__ W,
                      const float* __restrict__ b, float* __restrict__ out, int N) {
    int i = blockIdx.x * blockDim.x + threadIdx.x;
    if (i >= N * IN_DIM) return;
    int n = i >> 7, j = i & 127;
    const float* zr = z + (long)n * LATENT;
    float acc = b[j];
#pragma unroll
    for (int k = 0; k < LATENT; k++) acc += zr[k] * W[k * IN_DIM + j];
    out[i] = acc;
}

// ---------------- link: half-wave (32 lanes) per original edge ----------------
__global__ void k_link(const float* __restrict__ z, const int* __restrict__ ei,
                       const float* __restrict__ w, float* __restrict__ link, int E0) {
    int t = blockIdx.x * blockDim.x + threadIdx.x;
    int e = t >> 5;
    int c = t & 31;
    if (e >= E0) return;
    int s = ei[e], d = ei[E0 + e];
    float v = z[(long)s * LATENT + c] * z[(long)d * LATENT + c] * w[c];
    for (int off = 16; off; off >>= 1) v += __shfl_xor(v, off);
    if (c == 0) link[e] = v;
}

// ---------------- global add pool ----------------
__global__ void k_pool(const float* __restrict__ z, const int* __restrict__ batch,
                       float* __restrict__ gemb, int N) {
    int i = blockIdx.x * blockDim.x + threadIdx.x;
    if (i >= N * LATENT) return;
    int n = i >> 5, j = i & 31;
    atomicAdd(&gemb[batch[n] * LATENT + j], z[i]);
}

// ---------------- classifier ----------------
__global__ void k_cls(const float* __restrict__ g, const float* __restrict__ W,
                      const float* __restrict__ b, float* __restrict__ out) {
    int i = blockIdx.x * blockDim.x + threadIdx.x;
    if (i >= NUM_GRAPHS * NUM_CLASSES) return;
    int gi = i / NUM_CLASSES, j = i % NUM_CLASSES;
    float acc = b[j];
#pragma unroll
    for (int k = 0; k < LATENT; k++) acc += g[gi * LATENT + k] * W[k * NUM_CLASSES + j];
    out[i] = acc;
}

extern "C" void kernel_launch(void* const* d_in, const int* in_sizes, int n_in, void* d_out,
                              int out_size, void* d_ws, size_t ws_size, hipStream_t stream) {
    const float* x = (const float*)d_in[0];
    const int* ei = (const int*)d_in[1];
    const float* ea = (const float*)d_in[2];
    const int* batch = (const int*)d_in[3];
    const float* Wl0 = (const float*)d_in[4];
    const float* Wr0 = (const float*)d_in[5];
    const float* We0 = (const float*)d_in[6];
    const float* att0 = (const float*)d_in[7];
    const float* b0 = (const float*)d_in[8];
    const float* Wl1 = (const float*)d_in[9];
    const float* Wr1 = (const float*)d_in[10];
    const float* We1 = (const float*)d_in[11];
    const float* att1 = (const float*)d_in[12];
    const float* b1 = (const float*)d_in[13];
    const float* Wmu = (const float*)d_in[14];
    const float* bmu = (const float*)d_in[15];
    const float* Wdec = (const float*)d_in[16];
    const float* bdec = (const float*)d_in[17];
    const float* Wcls = (const float*)d_in[18];
    const float* bcls = (const float*)d_in[19];
    const float* weight = (const float*)d_in[20];

    const int N = in_sizes[0] / IN_DIM;  // 50000
    const int E0 = in_sizes[1] / 2;      // 400000

    // workspace layout (16B-aligned chunks)
    float* ws = (float*)d_ws;
    size_t o = 0;
    float* A = ws + o; o += (size_t)N * HC;       // xl  [N,256]
    float* B = ws + o; o += (size_t)N * HC;       // xr  [N,256]
    float4* csr_a = (float4*)(ws + o); o += (size_t)E0 * 4;
    int* csr_src = (int*)(ws + o); o += E0;
    int* deg = (int*)(ws + o); o += N;
    int* coff = (int*)(ws + o); o += N;
    int* cur = (int*)(ws + o); o += N;
    int* bsum = (int*)(ws + o); o += 256;
    float* G = ws + o; o += (size_t)N * HIDDEN;   // layer output h
    float* easum = ws + o; o += 16;
    float* gemb = ws + o; o += NUM_GRAPHS * LATENT;

    // output layout: z | recon | link | logits
    float* out = (float*)d_out;
    float* z_out = out;
    float* recon_out = out + (size_t)N * LATENT;
    float* link_out = recon_out + (size_t)N * IN_DIM;
    float* logits_out = link_out + (size_t)E0;

    const int TB = 256;
    const int nb = (N + 255) / 256;  // scan blocks (<=256)
    const int nodeBlocks = (N * 64 + TB - 1) / TB;  // one wave per node
    const float invE = 1.f / (float)E0;

    // ---- init + CSR build (shared by both layers) ----
    hipMemsetAsync(deg, 0, (size_t)N * sizeof(int), stream);
    hipMemsetAsync(easum, 0, 16 * sizeof(float), stream);
    hipMemsetAsync(gemb, 0, NUM_GRAPHS * LATENT * sizeof(float), stream);
    k_easum<<<256, TB, 0, stream>>>(ea, E0, easum);
    k_hist<<<(E0 + TB - 1) / TB, TB, 0, stream>>>(ei, deg, E0);
    k_scan1<<<nb, 256, 0, stream>>>(deg, coff, bsum, N);
    k_scan2<<<1, 256, 0, stream>>>(bsum, nb);
    k_scan3<<<nb, 256, 0, stream>>>(coff, bsum, cur, N);
    k_scatter<<<(E0 + TB - 1) / TB, TB, 0, stream>>>(ei, ea, cur, csr_src, csr_a, E0);

    // ---- layer 0 ----
    k_dual_gemm<IN_DIM, 8><<<(N + 7) / 8, TB, 0, stream>>>(x, Wl0, Wr0, A, B, N);
    k_gat<<<nodeBlocks, TB, 0, stream>>>(A, B, csr_src, csr_a, coff, deg, easum, invE, We0,
                                         att0, b0, G, N);

    // ---- layer 1 ----
    k_dual_gemm<HIDDEN, 8><<<(N + 7) / 8, TB, 0, stream>>>(G, Wl1, Wr1, A, B, N);
    k_gat<<<nodeBlocks, TB, 0, stream>>>(A, B, csr_src, csr_a, coff, deg, easum, invE, We1,
                                         att1, b1, G, N);

    // ---- heads ----
    k_mu<<<(N * LATENT + TB - 1) / TB, TB, 0, stream>>>(G, Wmu, bmu, z_out, N);
    k_dec<<<(N * IN_DIM + TB - 1) / TB, TB, 0, stream>>>(z_out, Wdec, bdec, recon_out, N);
    k_link<<<(E0 * 32 + TB - 1) / TB, TB, 0, stream>>>(z_out, ei, weight, link_out, E0);
    k_pool<<<(N * LATENT + TB - 1) / TB, TB, 0, stream>>>(z_out, batch, gemb, N);
    k_cls<<<(NUM_GRAPHS * NUM_CLASSES + TB - 1) / TB, TB, 0, stream>>>(gemb, Wcls, bcls,
                                                                       logits_out);
}

// Round 3
// 751.989 us; speedup vs baseline: 1.5060x; 1.0150x over previous
//
#include <hip/hip_runtime.h>
#include <math.h>

#define HIDDEN 64
#define LATENT 32
#define HEADS 4
#define IN_DIM 128
#define NUM_CLASSES 10
#define NUM_GRAPHS 64
#define NEG_SLOPE 0.2f
#define HC 256  // HEADS*HIDDEN

// ---------------- utility ----------------
// sum edge_attr columns (3) -> ea_sum[3]
__global__ void k_easum(const float* __restrict__ ea, int E, float* __restrict__ ea_sum) {
    float s0 = 0.f, s1 = 0.f, s2 = 0.f;
    for (int e = blockIdx.x * blockDim.x + threadIdx.x; e < E; e += gridDim.x * blockDim.x) {
        s0 += ea[e * 3 + 0];
        s1 += ea[e * 3 + 1];
        s2 += ea[e * 3 + 2];
    }
    for (int off = 32; off; off >>= 1) {
        s0 += __shfl_xor(s0, off);
        s1 += __shfl_xor(s1, off);
        s2 += __shfl_xor(s2, off);
    }
    if ((threadIdx.x & 63) == 0) {
        atomicAdd(&ea_sum[0], s0);
        atomicAdd(&ea_sum[1], s1);
        atomicAdd(&ea_sum[2], s2);
    }
}

// ---------------- CSR build ----------------
__global__ void k_hist(const int* __restrict__ ei, int* __restrict__ deg, int E0) {
    int e = blockIdx.x * blockDim.x + threadIdx.x;
    if (e < E0) atomicAdd(&deg[ei[E0 + e]], 1);
}

__global__ void k_scan1(const int* __restrict__ deg, int* __restrict__ off,
                        int* __restrict__ bsum, int N) {
    __shared__ int sh[256];
    int t = threadIdx.x, i = blockIdx.x * 256 + t;
    int v = (i < N) ? deg[i] : 0;
    sh[t] = v;
    __syncthreads();
    for (int d = 1; d < 256; d <<= 1) {
        int x = (t >= d) ? sh[t - d] : 0;
        __syncthreads();
        sh[t] += x;
        __syncthreads();
    }
    if (i < N) off[i] = sh[t] - v;  // exclusive
    if (t == 255) bsum[blockIdx.x] = sh[255];
}

__global__ void k_scan2(int* __restrict__ bsum, int nb) {
    __shared__ int sh[256];
    int t = threadIdx.x;
    int v = (t < nb) ? bsum[t] : 0;
    sh[t] = v;
    __syncthreads();
    for (int d = 1; d < 256; d <<= 1) {
        int x = (t >= d) ? sh[t - d] : 0;
        __syncthreads();
        sh[t] += x;
        __syncthreads();
    }
    if (t < nb) bsum[t] = sh[t] - v;  // exclusive block offsets
}

__global__ void k_scan3(int* __restrict__ off, const int* __restrict__ bsum,
                        int* __restrict__ cur, int N) {
    int i = blockIdx.x * 256 + threadIdx.x;
    if (i >= N) return;
    int o = off[i] + bsum[blockIdx.x];
    off[i] = o;
    cur[i] = o;
}

__global__ void k_scatter(const int* __restrict__ ei, const float* __restrict__ ea,
                          int* __restrict__ cur, int* __restrict__ csr_src,
                          float4* __restrict__ csr_a, int E0) {
    int e = blockIdx.x * blockDim.x + threadIdx.x;
    if (e >= E0) return;
    int dst = ei[E0 + e];
    int pos = atomicAdd(&cur[dst], 1);
    csr_src[pos] = ei[e];
    csr_a[pos] = make_float4(ea[e * 3], ea[e * 3 + 1], ea[e * 3 + 2], 0.f);
}

// ---------------- register-tiled GEMM: out-tile 128 nodes x 128 cols ----------------
// grid.y = n_tile: 0,1 -> Wl cols 0-127/128-255 into xl; 2,3 -> Wr into xr.
// 256 threads, 8x8 micro-tile. X-tile staged transposed in LDS [k][node] stride 132.
// W read directly from global (L1/L2 resident, broadcast across blocks).
template <int K>
__global__ __launch_bounds__(256, 2) void k_gemm(const float* __restrict__ X,
                                                 const float* __restrict__ Wl,
                                                 const float* __restrict__ Wr,
                                                 float* __restrict__ xl, float* __restrict__ xr,
                                                 int N) {
    constexpr int KC = 64;          // k-chunk
    constexpr int PAD = 132;        // row stride (16B aligned, bank-spread)
    __shared__ float sx[KC * PAD];  // 33 KB

    const int M0 = blockIdx.x * 128;
    const int nt = blockIdx.y;
    const float* W = ((nt < 2) ? Wl : Wr) + (nt & 1) * 128;
    float* out = ((nt < 2) ? xl : xr) + (nt & 1) * 128;

    const int t = threadIdx.x;
    const int tr = t >> 4;   // node group 0..15
    const int tc = t & 15;   // col group 0..15

    float acc[8][8];
#pragma unroll
    for (int i = 0; i < 8; i++)
#pragma unroll
        for (int j = 0; j < 8; j++) acc[i][j] = 0.f;

    const int kq = t & 15;    // float4 index within 64-float chunk row
    const int nsub = t >> 4;  // 0..15

    for (int kc0 = 0; kc0 < K; kc0 += KC) {
        // ---- stage X chunk transposed ----
        __syncthreads();
#pragma unroll
        for (int pass = 0; pass < 8; ++pass) {
            int node = pass * 16 + nsub;
            int gn = M0 + node;
            float4 v = make_float4(0.f, 0.f, 0.f, 0.f);
            if (gn < N) v = ((const float4*)(X + (size_t)gn * K + kc0))[kq];
            int k = kq * 4;
            sx[(k + 0) * PAD + node] = v.x;
            sx[(k + 1) * PAD + node] = v.y;
            sx[(k + 2) * PAD + node] = v.z;
            sx[(k + 3) * PAD + node] = v.w;
        }
        __syncthreads();

        const float* Wc = W + (size_t)kc0 * HC;
#pragma unroll 4
        for (int k = 0; k < KC; ++k) {
            float4 a0 = *(const float4*)&sx[k * PAD + tr * 8];
            float4 a1 = *(const float4*)&sx[k * PAD + tr * 8 + 4];
            float4 b0 = *(const float4*)&Wc[(size_t)k * HC + tc * 8];
            float4 b1 = *(const float4*)&Wc[(size_t)k * HC + tc * 8 + 4];
            float a[8] = {a0.x, a0.y, a0.z, a0.w, a1.x, a1.y, a1.z, a1.w};
            float b[8] = {b0.x, b0.y, b0.z, b0.w, b1.x, b1.y, b1.z, b1.w};
#pragma unroll
            for (int i = 0; i < 8; i++)
#pragma unroll
                for (int j = 0; j < 8; j++) acc[i][j] += a[i] * b[j];
        }
    }

#pragma unroll
    for (int i = 0; i < 8; i++) {
        int gn = M0 + tr * 8 + i;
        if (gn < N) {
            float* p = out + (size_t)gn * HC + tc * 8;
            ((float4*)p)[0] = make_float4(acc[i][0], acc[i][1], acc[i][2], acc[i][3]);
            ((float4*)p)[1] = make_float4(acc[i][4], acc[i][5], acc[i][6], acc[i][7]);
        }
    }
}

// ---------------- fused GATv2 layer: wave per node, online softmax ----------------
// lane L holds cols idx = 4L..4L+3 of the 256-wide row; head h = L>>4
__global__ void k_gat(const float* __restrict__ xl, const float* __restrict__ xr,
                      const int* __restrict__ csr_src, const float4* __restrict__ csr_a,
                      const int* __restrict__ off, const int* __restrict__ deg,
                      const float* __restrict__ easum, float invE,
                      const float* __restrict__ We, const float* __restrict__ att,
                      const float* __restrict__ bias, float* __restrict__ out, int N) {
    int wid = (blockIdx.x * blockDim.x + threadIdx.x) >> 6;
    int L = threadIdx.x & 63;
    if (wid >= N) return;
    int n = wid;

    float4 xr4 = ((const float4*)(xr + (size_t)n * HC))[L];
    float4 w0 = ((const float4*)We)[L];
    float4 w1 = ((const float4*)(We + HC))[L];
    float4 w2 = ((const float4*)(We + 2 * HC))[L];
    float4 at = ((const float4*)att)[L];
    float am0 = easum[0] * invE, am1 = easum[1] * invE, am2 = easum[2] * invE;

    float m = -INFINITY, d = 0.f;
    float acc0 = 0.f, acc1 = 0.f, acc2 = 0.f, acc3 = 0.f;
    int base = off[n], cnt = deg[n];

    for (int i = -1; i < cnt; i++) {
        int src;
        float a0, a1, a2;
        if (i < 0) {  // self loop, mean edge attr
            src = n;
            a0 = am0; a1 = am1; a2 = am2;
        } else {
            src = csr_src[base + i];
            float4 a = csr_a[base + i];
            a0 = a.x; a1 = a.y; a2 = a.z;
        }
        float4 xs = ((const float4*)(xl + (size_t)src * HC))[L];
        float s0 = xs.x + xr4.x + (a0 * w0.x + a1 * w1.x + a2 * w2.x);
        float s1 = xs.y + xr4.y + (a0 * w0.y + a1 * w1.y + a2 * w2.y);
        float s2 = xs.z + xr4.z + (a0 * w0.z + a1 * w1.z + a2 * w2.z);
        float s3 = xs.w + xr4.w + (a0 * w0.w + a1 * w1.w + a2 * w2.w);
        s0 = (s0 > 0.f) ? s0 : NEG_SLOPE * s0;
        s1 = (s1 > 0.f) ? s1 : NEG_SLOPE * s1;
        s2 = (s2 > 0.f) ? s2 : NEG_SLOPE * s2;
        s3 = (s3 > 0.f) ? s3 : NEG_SLOPE * s3;
        float p = s0 * at.x + s1 * at.y + s2 * at.z + s3 * at.w;
        // segmented butterfly over the 16 lanes of this head
        p += __shfl_xor(p, 1);
        p += __shfl_xor(p, 2);
        p += __shfl_xor(p, 4);
        p += __shfl_xor(p, 8);
        // online softmax update
        float mn = fmaxf(m, p);
        float sc = __expf(m - mn);
        float ex = __expf(p - mn);
        d = d * sc + ex;
        acc0 = acc0 * sc + ex * xs.x;
        acc1 = acc1 * sc + ex * xs.y;
        acc2 = acc2 * sc + ex * xs.z;
        acc3 = acc3 * sc + ex * xs.w;
        m = mn;
    }
    float inv_d = 1.f / d;
    float v0 = acc0 * inv_d, v1 = acc1 * inv_d, v2 = acc2 * inv_d, v3 = acc3 * inv_d;
    // head-mean: sum over lanes L^16, L^32
    v0 += __shfl_xor(v0, 16); v1 += __shfl_xor(v1, 16);
    v2 += __shfl_xor(v2, 16); v3 += __shfl_xor(v3, 16);
    v0 += __shfl_xor(v0, 32); v1 += __shfl_xor(v1, 32);
    v2 += __shfl_xor(v2, 32); v3 += __shfl_xor(v3, 32);
    if (L < 16) {
        float4 bx = ((const float4*)bias)[L];
        float4 o;
        o.x = fmaxf(0.25f * v0 + bx.x, 0.f);
        o.y = fmaxf(0.25f * v1 + bx.y, 0.f);
        o.z = fmaxf(0.25f * v2 + bx.z, 0.f);
        o.w = fmaxf(0.25f * v3 + bx.w, 0.f);
        ((float4*)(out + (size_t)n * HIDDEN))[L] = o;
    }
}

// ---------------- z = h @ W_mu + b_mu  (64 -> 32) ----------------
__global__ void k_mu(const float* __restrict__ h, const float* __restrict__ Wmu,
                     const float* __restrict__ bmu, float* __restrict__ z, int N) {
    int i = blockIdx.x * blockDim.x + threadIdx.x;
    if (i >= N * LATENT) return;
    int n = i >> 5, j = i & 31;
    const float* hr = h + (long)n * 64;
    float acc = bmu[j];
#pragma unroll
    for (int k = 0; k < 64; k++) acc += hr[k] * Wmu[k * LATENT + j];
    z[i] = acc;
}

// ---------------- recon = z @ W_dec + b_dec  (32 -> 128) ----------------
__global__ void k_dec(const float* __restrict__ z, const float* __restrict__ W,
                      const float* __restrict__ b, float* __restrict__ out, int N) {
    int i = blockIdx.x * blockDim.x + threadIdx.x;
    if (i >= N * IN_DIM) return;
    int n = i >> 7, j = i & 127;
    const float* zr = z + (long)n * LATENT;
    float acc = b[j];
#pragma unroll
    for (int k = 0; k < LATENT; k++) acc += zr[k] * W[k * IN_DIM + j];
    out[i] = acc;
}

// ---------------- link: half-wave (32 lanes) per original edge ----------------
__global__ void k_link(const float* __restrict__ z, const int* __restrict__ ei,
                       const float* __restrict__ w, float* __restrict__ link, int E0) {
    int t = blockIdx.x * blockDim.x + threadIdx.x;
    int e = t >> 5;
    int c = t & 31;
    if (e >= E0) return;
    int s = ei[e], d = ei[E0 + e];
    float v = z[(long)s * LATENT + c] * z[(long)d * LATENT + c] * w[c];
    for (int off = 16; off; off >>= 1) v += __shfl_xor(v, off);
    if (c == 0) link[e] = v;
}

// ---------------- global add pool ----------------
__global__ void k_pool(const float* __restrict__ z, const int* __restrict__ batch,
                       float* __restrict__ gemb, int N) {
    int i = blockIdx.x * blockDim.x + threadIdx.x;
    if (i >= N * LATENT) return;
    int n = i >> 5, j = i & 31;
    atomicAdd(&gemb[batch[n] * LATENT + j], z[i]);
}

// ---------------- classifier ----------------
__global__ void k_cls(const float* __restrict__ g, const float* __restrict__ W,
                      const float* __restrict__ b, float* __restrict__ out) {
    int i = blockIdx.x * blockDim.x + threadIdx.x;
    if (i >= NUM_GRAPHS * NUM_CLASSES) return;
    int gi = i / NUM_CLASSES, j = i % NUM_CLASSES;
    float acc = b[j];
#pragma unroll
    for (int k = 0; k < LATENT; k++) acc += g[gi * LATENT + k] * W[k * NUM_CLASSES + j];
    out[i] = acc;
}

extern "C" void kernel_launch(void* const* d_in, const int* in_sizes, int n_in, void* d_out,
                              int out_size, void* d_ws, size_t ws_size, hipStream_t stream) {
    const float* x = (const float*)d_in[0];
    const int* ei = (const int*)d_in[1];
    const float* ea = (const float*)d_in[2];
    const int* batch = (const int*)d_in[3];
    const float* Wl0 = (const float*)d_in[4];
    const float* Wr0 = (const float*)d_in[5];
    const float* We0 = (const float*)d_in[6];
    const float* att0 = (const float*)d_in[7];
    const float* b0 = (const float*)d_in[8];
    const float* Wl1 = (const float*)d_in[9];
    const float* Wr1 = (const float*)d_in[10];
    const float* We1 = (const float*)d_in[11];
    const float* att1 = (const float*)d_in[12];
    const float* b1 = (const float*)d_in[13];
    const float* Wmu = (const float*)d_in[14];
    const float* bmu = (const float*)d_in[15];
    const float* Wdec = (const float*)d_in[16];
    const float* bdec = (const float*)d_in[17];
    const float* Wcls = (const float*)d_in[18];
    const float* bcls = (const float*)d_in[19];
    const float* weight = (const float*)d_in[20];

    const int N = in_sizes[0] / IN_DIM;  // 50000
    const int E0 = in_sizes[1] / 2;      // 400000

    // workspace layout (16B-aligned chunks)
    float* ws = (float*)d_ws;
    size_t o = 0;
    float* A = ws + o; o += (size_t)N * HC;       // xl  [N,256]
    float* B = ws + o; o += (size_t)N * HC;       // xr  [N,256]
    float4* csr_a = (float4*)(ws + o); o += (size_t)E0 * 4;
    int* csr_src = (int*)(ws + o); o += E0;
    int* deg = (int*)(ws + o); o += N;
    int* coff = (int*)(ws + o); o += N;
    int* cur = (int*)(ws + o); o += N;
    int* bsum = (int*)(ws + o); o += 256;
    float* G = ws + o; o += (size_t)N * HIDDEN;   // layer output h
    float* easum = ws + o; o += 16;
    float* gemb = ws + o; o += NUM_GRAPHS * LATENT;

    // output layout: z | recon | link | logits
    float* out = (float*)d_out;
    float* z_out = out;
    float* recon_out = out + (size_t)N * LATENT;
    float* link_out = recon_out + (size_t)N * IN_DIM;
    float* logits_out = link_out + (size_t)E0;

    const int TB = 256;
    const int nb = (N + 255) / 256;                 // scan blocks (<=256)
    const int nodeBlocks = (N * 64 + TB - 1) / TB;  // one wave per node
    const float invE = 1.f / (float)E0;
    const dim3 gemmGrid((N + 127) / 128, 4);

    // ---- init + CSR build (shared by both layers) ----
    hipMemsetAsync(deg, 0, (size_t)N * sizeof(int), stream);
    hipMemsetAsync(easum, 0, 16 * sizeof(float), stream);
    hipMemsetAsync(gemb, 0, NUM_GRAPHS * LATENT * sizeof(float), stream);
    k_easum<<<256, TB, 0, stream>>>(ea, E0, easum);
    k_hist<<<(E0 + TB - 1) / TB, TB, 0, stream>>>(ei, deg, E0);
    k_scan1<<<nb, 256, 0, stream>>>(deg, coff, bsum, N);
    k_scan2<<<1, 256, 0, stream>>>(bsum, nb);
    k_scan3<<<nb, 256, 0, stream>>>(coff, bsum, cur, N);
    k_scatter<<<(E0 + TB - 1) / TB, TB, 0, stream>>>(ei, ea, cur, csr_src, csr_a, E0);

    // ---- layer 0 ----
    k_gemm<IN_DIM><<<gemmGrid, TB, 0, stream>>>(x, Wl0, Wr0, A, B, N);
    k_gat<<<nodeBlocks, TB, 0, stream>>>(A, B, csr_src, csr_a, coff, deg, easum, invE, We0,
                                         att0, b0, G, N);

    // ---- layer 1 ----
    k_gemm<HIDDEN><<<gemmGrid, TB, 0, stream>>>(G, Wl1, Wr1, A, B, N);
    k_gat<<<nodeBlocks, TB, 0, stream>>>(A, B, csr_src, csr_a, coff, deg, easum, invE, We1,
                                         att1, b1, G, N);

    // ---- heads ----
    k_mu<<<(N * LATENT + TB - 1) / TB, TB, 0, stream>>>(G, Wmu, bmu, z_out, N);
    k_dec<<<(N * IN_DIM + TB - 1) / TB, TB, 0, stream>>>(z_out, Wdec, bdec, recon_out, N);
    k_link<<<(E0 * 32 + TB - 1) / TB, TB, 0, stream>>>(z_out, ei, weight, link_out, E0);
    k_pool<<<(N * LATENT + TB - 1) / TB, TB, 0, stream>>>(z_out, batch, gemb, N);
    k_cls<<<(NUM_GRAPHS * NUM_CLASSES + TB - 1) / TB, TB, 0, stream>>>(gemb, Wcls, bcls,
                                                                       logits_out);
}